// Round 3
// baseline (2478.398 us; speedup 1.0000x reference)
//
#include <hip/hip_runtime.h>
#include <hip/hip_bf16.h>

#define N_NODES 30000
#define E_EDGES 480000
#define KSUB 32
#define NPAIR 16384

typedef __hip_bfloat16 bf16;
typedef __bf16 bf16x8 __attribute__((ext_vector_type(8)));
typedef float floatx4 __attribute__((ext_vector_type(4)));

static __device__ __forceinline__ unsigned short f2bu(float f) {
    // round-to-nearest-even f32 -> bf16 (finite inputs only)
    unsigned int u = __float_as_uint(f);
    unsigned int r = (u + 0x7fffu + ((u >> 16) & 1u)) >> 16;
    return (unsigned short)r;
}

// ---------------- weight transpose f32 -> bf16 (+K padding with zeros) ------
__global__ void transpose_pad(const float* __restrict__ W, int K, int Nd,
                              unsigned short* __restrict__ Wt, int Kpad) {
    int t = blockIdx.x * 256 + threadIdx.x;
    if (t >= Nd * Kpad) return;
    int n = t / Kpad, k = t - n * Kpad;
    Wt[t] = (k < K) ? f2bu(W[(size_t)k * Nd + n]) : (unsigned short)0;
}

// ---------------- CSR build ----------------
__global__ void edge_hist(const int* __restrict__ dst, int* __restrict__ deg) {
    int e = blockIdx.x * 256 + threadIdx.x;
    if (e < E_EDGES) atomicAdd(&deg[dst[e]], 1);
}

__global__ void scan_kernel(const int* __restrict__ deg, int N,
                            int* __restrict__ row_start, int* __restrict__ cursor) {
    __shared__ int sh[1024];
    int t = threadIdx.x;
    int chunk = (N + 1023) >> 10;
    int lo = t * chunk;
    int hi = lo + chunk; if (hi > N) hi = N;
    if (lo > N) lo = N;
    int s = 0;
    for (int i = lo; i < hi; i++) s += deg[i];
    sh[t] = s;
    __syncthreads();
    for (int off = 1; off < 1024; off <<= 1) {
        int v = (t >= off) ? sh[t - off] : 0;
        __syncthreads();
        sh[t] += v;
        __syncthreads();
    }
    int run = (t == 0) ? 0 : sh[t - 1];
    for (int i = lo; i < hi; i++) {
        row_start[i] = run; cursor[i] = run; run += deg[i];
    }
    if (t == 1023) row_start[N] = run;
}

__global__ void edge_scatter(const int* __restrict__ src, const int* __restrict__ dst,
                             int* __restrict__ cursor, int* __restrict__ csr_src) {
    int e = blockIdx.x * 256 + threadIdx.x;
    if (e < E_EDGES) {
        int p = atomicAdd(&cursor[dst[e]], 1);
        if (p >= 0 && p < E_EDGES) csr_src[p] = src[e];
    }
}

// ---------------- CSR aggregation (f32): Y[i] = (addCenter? X[i]:0) + sum_{j in N(i)} X[j]
__global__ void csr_agg(const float* __restrict__ X, int ldx, int D,
                        const int* __restrict__ row_start, const int* __restrict__ csr_src,
                        float* __restrict__ Y, int ldy, int Dout, int addCenter) {
    int node = blockIdx.x * 4 + (threadIdx.x >> 6);
    if (node >= N_NODES) return;
    int lane = threadIdx.x & 63;
    int s0 = row_start[node], s1 = row_start[node + 1];
    if (s0 < 0) s0 = 0;
    if (s1 > E_EDGES) s1 = E_EDGES;
    for (int c0 = 0; c0 < Dout; c0 += 64) {
        int c = c0 + lane;
        float acc = 0.0f;
        if (c < D) {
            if (addCenter) acc = X[(size_t)node * ldx + c];
            for (int j = s0; j < s1; j++) {
                int s = csr_src[j];
                if ((unsigned)s >= (unsigned)N_NODES) s = 0;
                acc += X[(size_t)s * ldx + c];
            }
        }
        if (c < Dout) Y[(size_t)node * ldy + c] = acc;
    }
}

// ---------------- LayerNorm(+bias)(+optional agg)(+optional relu), f32, one wave/row
// In-place safe (Out may alias Y or Agg): each thread reads its columns before writing.
template <int D>
__global__ void ln_relu(const float* __restrict__ Y, const float* __restrict__ Agg,
                        const float* __restrict__ bias, float* __restrict__ Out, int doRelu) {
    int row = blockIdx.x * 4 + (threadIdx.x >> 6);
    if (row >= N_NODES) return;
    int lane = threadIdx.x & 63;
    constexpr int NV = D / 64;
    float v[NV];
    float s = 0.0f;
#pragma unroll
    for (int i = 0; i < NV; i++) {
        int c = i * 64 + lane;
        float tv = Y[(size_t)row * D + c] + bias[c];
        if (Agg) tv += Agg[(size_t)row * D + c];
        v[i] = tv; s += tv;
    }
    for (int o = 32; o; o >>= 1) s += __shfl_xor(s, o);
    float mean = s / (float)D;
    float q = 0.0f;
#pragma unroll
    for (int i = 0; i < NV; i++) { float d = v[i] - mean; q += d * d; }
    for (int o = 32; o; o >>= 1) q += __shfl_xor(q, o);
    float rs = rsqrtf(q / (float)D + 1e-5f);
#pragma unroll
    for (int i = 0; i < NV; i++) {
        int c = i * 64 + lane;
        float o = (v[i] - mean) * rs;
        if (doRelu && o < 0.0f) o = 0.0f;
        Out[(size_t)row * D + c] = o;
    }
}

// ---------------- MFMA GEMM: C[M,Nd](f32) = A[M,K](f32, cast->bf16) * Bt[Nd,K](bf16)^T (+bias)
// 128x128 tile, BK=64, 256 threads (2x2 waves of 64x64), 16x16x32 bf16 MFMA.
// A staged via float4 pair -> RNE bf16 pack -> LDS; padded LDS stride 72 shorts.
__global__ __launch_bounds__(256, 2) void gemm_bt(
    const float* __restrict__ A, int lda, const unsigned short* __restrict__ Bt,
    int M, int K, float* __restrict__ C, int ldc, const float* __restrict__ bias) {
    __shared__ __align__(16) unsigned short As[128 * 72];
    __shared__ __align__(16) unsigned short Bs[128 * 72];
    const int t = threadIdx.x;
    const int lane = t & 63;
    const int wave = t >> 6;
    const int wm = wave >> 1, wn = wave & 1;
    const int quad = lane >> 4, m16 = lane & 15;
    const int bm = blockIdx.x, bn = blockIdx.y;

    floatx4 acc[4][4];
#pragma unroll
    for (int i = 0; i < 4; i++)
#pragma unroll
        for (int j = 0; j < 4; j++)
#pragma unroll
            for (int r = 0; r < 4; r++) acc[i][j][r] = 0.0f;

    union Pk { unsigned short h[8]; uint4 v; };

    for (int k0 = 0; k0 < K; k0 += 64) {
        // stage A tile: 128 rows x 64 k = 1024 granules of 8 elems; 4 per thread
#pragma unroll
        for (int i = 0; i < 4; i++) {
            int q = i * 256 + t;
            int r = q >> 3, g = q & 7;
            int grow = bm * 128 + r;
            uint4 val = make_uint4(0u, 0u, 0u, 0u);
            if (grow < M) {
                const float* ap = A + (size_t)grow * lda + k0 + g * 8;
                float4 f0 = *reinterpret_cast<const float4*>(ap);
                float4 f1 = *reinterpret_cast<const float4*>(ap + 4);
                Pk pk;
                pk.h[0] = f2bu(f0.x); pk.h[1] = f2bu(f0.y);
                pk.h[2] = f2bu(f0.z); pk.h[3] = f2bu(f0.w);
                pk.h[4] = f2bu(f1.x); pk.h[5] = f2bu(f1.y);
                pk.h[6] = f2bu(f1.z); pk.h[7] = f2bu(f1.w);
                val = pk.v;
            }
            *reinterpret_cast<uint4*>(&As[r * 72 + g * 8]) = val;
        }
        // stage B tile (bf16 weights; rows always in range: Nd % 128 == 0)
#pragma unroll
        for (int i = 0; i < 4; i++) {
            int q = i * 256 + t;
            int r = q >> 3, g = q & 7;
            int grow = bn * 128 + r;
            uint4 val = *reinterpret_cast<const uint4*>(Bt + (size_t)grow * K + k0 + g * 8);
            *reinterpret_cast<uint4*>(&Bs[r * 72 + g * 8]) = val;
        }
        __syncthreads();
#pragma unroll
        for (int kk = 0; kk < 2; kk++) {
            bf16x8 af[4], bfr[4];
#pragma unroll
            for (int i = 0; i < 4; i++) {
                int r = wm * 64 + i * 16 + m16;
                af[i] = *reinterpret_cast<const bf16x8*>(&As[r * 72 + (kk * 4 + quad) * 8]);
            }
#pragma unroll
            for (int j = 0; j < 4; j++) {
                int r = wn * 64 + j * 16 + m16;
                bfr[j] = *reinterpret_cast<const bf16x8*>(&Bs[r * 72 + (kk * 4 + quad) * 8]);
            }
#pragma unroll
            for (int i = 0; i < 4; i++)
#pragma unroll
                for (int j = 0; j < 4; j++)
                    acc[i][j] = __builtin_amdgcn_mfma_f32_16x16x32_bf16(af[i], bfr[j], acc[i][j], 0, 0, 0);
        }
        __syncthreads();
    }
    // epilogue: C/D layout col=lane&15, row=quad*4+reg (m89-verified)
#pragma unroll
    for (int i = 0; i < 4; i++) {
        int r0 = bm * 128 + wm * 64 + i * 16 + quad * 4;
#pragma unroll
        for (int j = 0; j < 4; j++) {
            int c = bn * 128 + wn * 64 + j * 16 + m16;
            float bia = bias ? bias[c] : 0.0f;
#pragma unroll
            for (int r = 0; r < 4; r++) {
                int row = r0 + r;
                if (row < M) C[(size_t)row * ldc + c] = acc[i][j][r] + bia;
            }
        }
    }
}

// ---------------- subgraph mean pool (f32)
__global__ void pool_kernel(const float* __restrict__ zn, const int* __restrict__ idx,
                            float* __restrict__ out) {
    int i = blockIdx.x;
    int c = threadIdx.x;  // 128
    float acc = 0.0f;
    for (int k = 0; k < KSUB; k++) {
        int s = idx[i * KSUB + k];
        if ((unsigned)s >= (unsigned)N_NODES) s = 0;
        acc += zn[(size_t)s * 128 + c];
    }
    out[(size_t)i * 128 + c] = acc * (1.0f / KSUB);
}

// ---------------- batch embedding MLP (f32): [N,8] -> relu 12 -> 16
__global__ void batch_emb_kernel(const float* __restrict__ bl, const float* __restrict__ W0,
                                 const float* __restrict__ b0, const float* __restrict__ W1,
                                 const float* __restrict__ b1, float* __restrict__ out) {
    int i = blockIdx.x * 256 + threadIdx.x;
    if (i >= N_NODES) return;
    float in[8];
#pragma unroll
    for (int d = 0; d < 8; d++) in[d] = bl[(size_t)i * 8 + d];
    float h[12];
#pragma unroll
    for (int j = 0; j < 12; j++) {
        float a = b0[j];
#pragma unroll
        for (int d = 0; d < 8; d++) a += in[d] * W0[d * 12 + j];
        h[j] = a > 0.0f ? a : 0.0f;
    }
#pragma unroll
    for (int j = 0; j < 16; j++) {
        float a = b1[j];
#pragma unroll
        for (int k = 0; k < 12; k++) a += h[k] * W1[k * 16 + j];
        out[(size_t)i * 16 + j] = a;
    }
}

// ---------------- concat z_node[128] ++ batch_emb[16] -> [144] (f32)
__global__ void concat_kernel(const float* __restrict__ zn, const float* __restrict__ be,
                              float* __restrict__ znb) {
    int i = blockIdx.x;
    int t = threadIdx.x;  // 192
    if (t < 128) znb[(size_t)i * 144 + t] = zn[(size_t)i * 128 + t];
    else if (t < 144) znb[(size_t)i * 144 + t] = be[(size_t)i * 16 + (t - 128)];
}

// ---------------- bilinear discriminator (f32)
__global__ void bilinear_kernel(const float* __restrict__ z_sub, const float* __restrict__ z_shf,
                                const float* __restrict__ W, const int* __restrict__ pos,
                                const int* __restrict__ neg, float* __restrict__ out_pos,
                                float* __restrict__ out_neg) {
    int p = blockIdx.x;
    int e = threadIdx.x;  // 128
    __shared__ float zp_sh[128];
    __shared__ float red[4];
    int ip = pos[p], ineg = neg[p];
    zp_sh[e] = z_sub[(size_t)ip * 128 + e];
    __syncthreads();
    float t = 0.0f;
    for (int d = 0; d < 128; d++) t += zp_sh[d] * W[d * 128 + e];
    float vp = t * z_shf[(size_t)ip * 128 + e];
    float vn = t * z_shf[(size_t)ineg * 128 + e];
    for (int o = 32; o; o >>= 1) { vp += __shfl_xor(vp, o); vn += __shfl_xor(vn, o); }
    int w = e >> 6;
    if ((e & 63) == 0) { red[w * 2] = vp; red[w * 2 + 1] = vn; }
    __syncthreads();
    if (e == 0) { out_pos[p] = red[0] + red[2]; out_neg[p] = red[1] + red[3]; }
}

// ---------------- batch discriminator MLP (f32): [N,128] -> relu 64 -> 8
__global__ void bd_kernel(const float* __restrict__ z_sub, const float* __restrict__ W0,
                          const float* __restrict__ b0, const float* __restrict__ W1,
                          const float* __restrict__ b1, float* __restrict__ out) {
    __shared__ float zsh[4][128];
    __shared__ float hsh[4][64];
    int w = threadIdx.x >> 6, lane = threadIdx.x & 63;
    int node = blockIdx.x * 4 + w;
    zsh[w][lane] = z_sub[(size_t)node * 128 + lane];
    zsh[w][64 + lane] = z_sub[(size_t)node * 128 + 64 + lane];
    __syncthreads();
    float h = b0[lane];
    for (int d = 0; d < 128; d++) h += zsh[w][d] * W0[d * 64 + lane];
    if (h < 0.0f) h = 0.0f;
    hsh[w][lane] = h;
    __syncthreads();
    if (lane < 8) {
        float o = b1[lane];
        for (int l = 0; l < 64; l++) o += hsh[w][l] * W1[l * 8 + lane];
        out[(size_t)node * 8 + lane] = o;
    }
}

extern "C" void kernel_launch(void* const* d_in, const int* in_sizes, int n_in,
                              void* d_out, int out_size, void* d_ws, size_t ws_size,
                              hipStream_t stream) {
    const float* x = (const float*)d_in[0];
    const float* x_shf = (const float*)d_in[1];
    const float* blab = (const float*)d_in[2];
    const float* encW0 = (const float*)d_in[3];
    const float* encb0 = (const float*)d_in[4];
    const float* encW1 = (const float*)d_in[5];
    const float* encb1 = (const float*)d_in[6];
    const float* decW0 = (const float*)d_in[7];
    const float* decb0 = (const float*)d_in[8];
    const float* decW1 = (const float*)d_in[9];
    const float* decb1 = (const float*)d_in[10];
    const float* beW0 = (const float*)d_in[11];
    const float* beb0 = (const float*)d_in[12];
    const float* beW1 = (const float*)d_in[13];
    const float* beb1 = (const float*)d_in[14];
    const float* bdW0 = (const float*)d_in[15];
    const float* bdb0 = (const float*)d_in[16];
    const float* bdW1 = (const float*)d_in[17];
    const float* bdb1 = (const float*)d_in[18];
    const float* bilW = (const float*)d_in[19];
    const int* eidx = (const int*)d_in[20];
    const int* subidx = (const int*)d_in[21];
    const int* posi = (const int*)d_in[22];
    const int* negi = (const int*)d_in[23];
    float* out = (float*)d_out;

    char* ws = (char*)d_ws;
    size_t off = 0;
    auto alloc = [&](size_t bytes) -> void* {
        void* p = ws + off;
        off += (bytes + 255) & ~(size_t)255;
        return p;
    };
    unsigned short* encW0t = (unsigned short*)alloc((size_t)512 * 1024 * 2);
    unsigned short* encW1t = (unsigned short*)alloc((size_t)128 * 512 * 2);
    unsigned short* decW0t = (unsigned short*)alloc((size_t)512 * 192 * 2);
    unsigned short* decW1t = (unsigned short*)alloc((size_t)1024 * 512 * 2);
    int* deg = (int*)alloc((size_t)N_NODES * 4);
    int* row_start = (int*)alloc((size_t)(N_NODES + 1) * 4);
    int* cursor = (int*)alloc((size_t)N_NODES * 4);
    int* csr_src = (int*)alloc((size_t)E_EDGES * 4);
    float* y0f = (float*)alloc((size_t)N_NODES * 512 * 4);    // enc/dec pre-act; dec h1 (in-place LN)
    float* agg0f = (float*)alloc((size_t)N_NODES * 512 * 4);  // enc agg + h1 (in-place); dec agg
    float* y1f = (float*)alloc((size_t)N_NODES * 128 * 4);    // aliased by znb after encoder
    float* agg1f = (float*)alloc((size_t)N_NODES * 128 * 4);  // aliased by znb/s1f after encoder
    float* znsf = (float*)alloc((size_t)N_NODES * 128 * 4);   // aliased by s1f after encoder
    float* znf = (float*)alloc((size_t)N_NODES * 128 * 4);    // persists into decoder
    float* bemb = (float*)alloc((size_t)N_NODES * 16 * 4);
    if (off > ws_size) return;  // workspace too small: fail cleanly (finite-zero signature)

    // decoder-phase aliases over the y1f/agg1f/znsf region (46.08 MB, all free after encoder)
    float* znb = y1f;                                          // 30000*144*4 = 17.28 MB
    float* s1f = (float*)((char*)y1f + (size_t)30000 * 144 * 4);  // 30000*192*4 = 23.04 MB

    const int* e_src = eidx;
    const int* e_dst = eidx + E_EDGES;

    // weight transposes f32 -> bf16 (pad K to multiple of 64 where needed)
    transpose_pad<<<(512 * 1024 + 255) / 256, 256, 0, stream>>>(encW0, 1024, 512, encW0t, 1024);
    transpose_pad<<<(128 * 512 + 255) / 256, 256, 0, stream>>>(encW1, 512, 128, encW1t, 512);
    transpose_pad<<<(512 * 192 + 255) / 256, 256, 0, stream>>>(decW0, 144, 512, decW0t, 192);
    transpose_pad<<<(1024 * 512 + 255) / 256, 256, 0, stream>>>(decW1, 512, 1024, decW1t, 512);

    // CSR build (keyed by dst, storing src)
    hipMemsetAsync(deg, 0, (size_t)N_NODES * 4, stream);
    edge_hist<<<E_EDGES / 256, 256, 0, stream>>>(e_dst, deg);
    scan_kernel<<<1, 1024, 0, stream>>>(deg, N_NODES, row_start, cursor);
    edge_scatter<<<E_EDGES / 256, 256, 0, stream>>>(e_src, e_dst, cursor, csr_src);

    dim3 gA(235, 4), gB(235, 1), gC(235, 4), gD(235, 8);

    // encoder, twice (x then x_shf); matmul-first so aggregation runs in the smaller dim
    for (int pass = 0; pass < 2; pass++) {
        const float* xin = pass ? x_shf : x;
        float* zn = pass ? znsf : znf;
        float* zsub_out = out + (pass ? 3840000 : 0);
        gemm_bt<<<gA, 256, 0, stream>>>(xin, 1024, encW0t, N_NODES, 1024, y0f, 512, nullptr);
        csr_agg<<<7500, 256, 0, stream>>>(y0f, 512, 512, row_start, csr_src, agg0f, 512, 512, 0);
        ln_relu<512><<<7500, 256, 0, stream>>>(y0f, agg0f, encb0, agg0f, 1);  // h1 := agg0f
        gemm_bt<<<gB, 256, 0, stream>>>(agg0f, 512, encW1t, N_NODES, 512, y1f, 128, nullptr);
        csr_agg<<<7500, 256, 0, stream>>>(y1f, 128, 128, row_start, csr_src, agg1f, 128, 128, 0);
        ln_relu<128><<<7500, 256, 0, stream>>>(y1f, agg1f, encb1, zn, 1);
        pool_kernel<<<30000, 128, 0, stream>>>(zn, subidx, zsub_out);
    }

    // batch embedding + concat (znb aliases y1f region — encoder temporaries are dead now)
    batch_emb_kernel<<<(N_NODES + 255) / 256, 256, 0, stream>>>(blab, beW0, beb0, beW1, beb1, bemb);
    concat_kernel<<<30000, 192, 0, stream>>>(znf, bemb, znb);

    // decoder (agg-first so aggregation runs in the smaller dim)
    csr_agg<<<7500, 256, 0, stream>>>(znb, 144, 144, row_start, csr_src, s1f, 192, 192, 1);
    gemm_bt<<<gC, 256, 0, stream>>>(s1f, 192, decW0t, N_NODES, 192, y0f, 512, nullptr);
    ln_relu<512><<<7500, 256, 0, stream>>>(y0f, nullptr, decb0, y0f, 1);  // in-place
    csr_agg<<<7500, 256, 0, stream>>>(y0f, 512, 512, row_start, csr_src, agg0f, 512, 512, 1);
    gemm_bt<<<gD, 256, 0, stream>>>(agg0f, 512, decW1t, N_NODES, 512, out + 7680000, 1024, decb1);

    // heads
    bilinear_kernel<<<NPAIR, 128, 0, stream>>>(out, out + 3840000, bilW, posi, negi,
                                               out + 38400000, out + 38416384);
    bd_kernel<<<7500, 256, 0, stream>>>(out, bdW0, bdb0, bdW1, bdb1, out + 38432768);
}